// Round 1
// baseline (896.710 us; speedup 1.0000x reference)
//
#include <hip/hip_runtime.h>

#define H 128
#define O 64
#define RELS 4

// out[n][o] = bias2[o]
__global__ void k_init_out(float* __restrict__ out, const float* __restrict__ bias2, int total) {
    int i = blockIdx.x * blockDim.x + threadIdx.x;
    if (i < total) out[i] = bias2[i & (O - 1)];
}

// histogram of dst -> deg (float counts)
__global__ void k_deg(const int* __restrict__ dst, float* __restrict__ deg, int E) {
    int i = blockIdx.x * blockDim.x + threadIdx.x;
    if (i < E) unsafeAtomicAdd(&deg[dst[i]], 1.0f);
}

// deg -> 1/max(deg,1) in place
__global__ void k_invdeg(float* __restrict__ deg, int n) {
    int i = blockIdx.x * blockDim.x + threadIdx.x;
    if (i < n) deg[i] = 1.0f / fmaxf(deg[i], 1.0f);
}

// one wave per edge: h1[dst] += embed[src] * invdeg[dst]   (H=128, 2 floats/lane)
__global__ void k_scatter1(const float* __restrict__ embed, const int* __restrict__ src,
                           const int* __restrict__ dst, const float* __restrict__ invdeg,
                           float* __restrict__ h1, int E) {
    int w = (blockIdx.x * blockDim.x + threadIdx.x) >> 6;
    int lane = threadIdx.x & 63;
    if (w >= E) return;
    int s = src[w], d = dst[w];
    float sc = invdeg[d];
    float2 v = *(const float2*)(embed + (size_t)s * H + lane * 2);
    float* p = h1 + (size_t)d * H + lane * 2;
    unsafeAtomicAdd(p,     v.x * sc);
    unsafeAtomicAdd(p + 1, v.y * sc);
}

// h1 = relu(h1 + bias1), vectorized float4
__global__ void k_biasrelu(float* __restrict__ h1, const float* __restrict__ bias1, int total4) {
    int i = blockIdx.x * blockDim.x + threadIdx.x;
    if (i >= total4) return;
    float4 v = ((float4*)h1)[i];
    int c = (i * 4) & (H - 1);
    v.x = fmaxf(v.x + bias1[c + 0], 0.f);
    v.y = fmaxf(v.y + bias1[c + 1], 0.f);
    v.z = fmaxf(v.z + bias1[c + 2], 0.f);
    v.w = fmaxf(v.w + bias1[c + 3], 0.f);
    ((float4*)h1)[i] = v;
}

// T[N,64] = A[N,128] @ W[128,64], f32, 64-row tile per block, 256 threads, 4x4 per thread
__global__ __launch_bounds__(256) void k_gemm(const float* __restrict__ A,
                                              const float* __restrict__ W,
                                              float* __restrict__ T, int N) {
    __shared__ float As[64 * 132];   // pad 128->132 to break bank conflicts
    __shared__ float Bs[128 * 64];
    int tid = threadIdx.x;
    int row0 = blockIdx.x * 64;

    const float4* W4 = (const float4*)W;
    float4* B4 = (float4*)Bs;
#pragma unroll
    for (int i = 0; i < 8; ++i) B4[tid + i * 256] = W4[tid + i * 256];

#pragma unroll
    for (int i = 0; i < 8; ++i) {
        int idx = (tid + i * 256) * 4;
        int rr = idx >> 7, cc = idx & 127;
        int grow = row0 + rr;
        float4 v = make_float4(0.f, 0.f, 0.f, 0.f);
        if (grow < N) v = *(const float4*)(A + (size_t)grow * H + cc);
        *(float4*)(As + rr * 132 + cc) = v;
    }
    __syncthreads();

    int ty = tid >> 4, tx = tid & 15;
    float acc[4][4] = {};
    for (int k = 0; k < 128; ++k) {
        float av[4];
#pragma unroll
        for (int i = 0; i < 4; ++i) av[i] = As[(ty * 4 + i) * 132 + k];
        float4 b = *(const float4*)(Bs + k * 64 + tx * 4);
#pragma unroll
        for (int i = 0; i < 4; ++i) {
            acc[i][0] += av[i] * b.x;
            acc[i][1] += av[i] * b.y;
            acc[i][2] += av[i] * b.z;
            acc[i][3] += av[i] * b.w;
        }
    }
#pragma unroll
    for (int i = 0; i < 4; ++i) {
        int grow = row0 + ty * 4 + i;
        if (grow < N) {
            float4 v = make_float4(acc[i][0], acc[i][1], acc[i][2], acc[i][3]);
            *(float4*)(T + (size_t)grow * O + tx * 4) = v;
        }
    }
}

// one wave per edge: out[dst] += T[src] * invdeg[dst]   (O=64, 1 float/lane)
__global__ void k_scatter2(const float* __restrict__ T, const int* __restrict__ src,
                           const int* __restrict__ dst, const float* __restrict__ invdeg,
                           float* __restrict__ out, int E) {
    int w = (blockIdx.x * blockDim.x + threadIdx.x) >> 6;
    int lane = threadIdx.x & 63;
    if (w >= E) return;
    int s = src[w], d = dst[w];
    float sc = invdeg[d];
    float v = T[(size_t)s * O + lane];
    unsafeAtomicAdd(out + (size_t)d * O + lane, v * sc);
}

extern "C" void kernel_launch(void* const* d_in, const int* in_sizes, int n_in,
                              void* d_out, int out_size, void* d_ws, size_t ws_size,
                              hipStream_t stream) {
    const float* embed  = (const float*)d_in[0];
    const float* weight = (const float*)d_in[1];
    const float* bias1  = (const float*)d_in[2];
    const float* bias2  = (const float*)d_in[3];
    const int*   esrc   = (const int*)d_in[4];
    const int*   edst   = (const int*)d_in[5];
    float* out = (float*)d_out;

    const int N = in_sizes[0] / H;
    const int E = in_sizes[4] / RELS;

    char* ws = (char*)d_ws;
    size_t sz_invdeg = (size_t)RELS * N * sizeof(float);
    size_t o1 = (sz_invdeg + 255) & ~(size_t)255;
    size_t sz_h1 = (size_t)N * H * sizeof(float);
    size_t o2 = (o1 + sz_h1 + 255) & ~(size_t)255;
    float* invdeg = (float*)ws;
    float* h1 = (float*)(ws + o1);
    float* T  = (float*)(ws + o2);
    // total ws need: o2 + N*O*4  (~78.4 MB)

    hipMemsetAsync(invdeg, 0, sz_invdeg, stream);
    hipMemsetAsync(h1, 0, sz_h1, stream);

    {   // out = bias2 broadcast
        int total = N * O;
        k_init_out<<<(total + 255) / 256, 256, 0, stream>>>(out, bias2, total);
    }
    for (int r = 0; r < RELS; ++r)
        k_deg<<<(E + 255) / 256, 256, 0, stream>>>(edst + (size_t)r * E, invdeg + (size_t)r * N, E);
    k_invdeg<<<(RELS * N + 255) / 256, 256, 0, stream>>>(invdeg, RELS * N);

    for (int r = 0; r < RELS; ++r)
        k_scatter1<<<(E + 3) / 4, 256, 0, stream>>>(embed, esrc + (size_t)r * E, edst + (size_t)r * E,
                                                    invdeg + (size_t)r * N, h1, E);

    k_biasrelu<<<(N * H / 4 + 255) / 256, 256, 0, stream>>>(h1, bias1, N * H / 4);

    for (int r = 0; r < RELS; ++r) {
        k_gemm<<<(N + 63) / 64, 256, 0, stream>>>(h1, weight + (size_t)r * H * O, T, N);
        k_scatter2<<<(E + 3) / 4, 256, 0, stream>>>(T, esrc + (size_t)r * E, edst + (size_t)r * E,
                                                    invdeg + (size_t)r * N, out, E);
    }
}

// Round 2
// 359.233 us; speedup vs baseline: 2.4962x; 2.4962x over previous
//
#include <hip/hip_runtime.h>

#define H 128
#define O 64
#define RELS 4

// ---------- CSR construction ----------

// histogram: cnt[r*N + dst] += 1 for one relation's dst list
__global__ void k_hist(const int* __restrict__ dst, int* __restrict__ cnt, int E) {
    int i = blockIdx.x * blockDim.x + threadIdx.x;
    if (i < E) atomicAdd(&cnt[dst[i]], 1);
}

// block-level exclusive scan: 1024 elements per block (256 thr x 4), block sums out
__global__ void k_scan1(const int* __restrict__ cnt, int* __restrict__ offs,
                        int* __restrict__ bsum, int n) {
    __shared__ int sh[256];
    int t = threadIdx.x;
    int base = blockIdx.x * 1024 + t * 4;
    int4 v = make_int4(0, 0, 0, 0);
    if (base + 3 < n) v = *(const int4*)(cnt + base);
    else {
        if (base < n)     v.x = cnt[base];
        if (base + 1 < n) v.y = cnt[base + 1];
        if (base + 2 < n) v.z = cnt[base + 2];
    }
    int s = v.x + v.y + v.z + v.w;
    sh[t] = s; __syncthreads();
    for (int off = 1; off < 256; off <<= 1) {
        int x = (t >= off) ? sh[t - off] : 0;
        __syncthreads();
        sh[t] += x;
        __syncthreads();
    }
    int incl = sh[t];
    int ex = incl - s;
    if (base < n)     offs[base]     = ex;
    if (base + 1 < n) offs[base + 1] = ex + v.x;
    if (base + 2 < n) offs[base + 2] = ex + v.x + v.y;
    if (base + 3 < n) offs[base + 3] = ex + v.x + v.y + v.z;
    if (t == 255) bsum[blockIdx.x] = incl;
}

// scan the block sums (nb <= 512) in one block, in place, exclusive
__global__ void k_scan2(int* __restrict__ bsum, int nb) {
    __shared__ int sh[512];
    int t = threadIdx.x;
    int s = (t < nb) ? bsum[t] : 0;
    sh[t] = s; __syncthreads();
    for (int off = 1; off < 512; off <<= 1) {
        int x = (t >= off) ? sh[t - off] : 0;
        __syncthreads();
        sh[t] += x;
        __syncthreads();
    }
    if (t < nb) bsum[t] = sh[t] - s;
}

// add block offsets, copy into cursor, write sentinel
__global__ void k_scan3(int* __restrict__ offs, int* __restrict__ cursor,
                        const int* __restrict__ bsum, int n, int total) {
    int i = blockIdx.x * blockDim.x + threadIdx.x;
    if (i < n) {
        int v = offs[i] + bsum[i >> 10];
        offs[i] = v;
        cursor[i] = v;
    }
    if (i == 0) offs[n] = total;
}

// scatter src ids into CSR order (cursor[r*N+dst] pre-set to offs)
__global__ void k_fill(const int* __restrict__ src, const int* __restrict__ dst,
                       int* __restrict__ cursor, int* __restrict__ ssrc, int E) {
    int i = blockIdx.x * blockDim.x + threadIdx.x;
    if (i < E) {
        int pos = atomicAdd(&cursor[dst[i]], 1);
        ssrc[pos] = src[i];
    }
}

// ---------- Layer 1: fused pull over all relations + bias + relu ----------
// one wave per node; lane covers 2 of the 128 features
__global__ void k_pull1(const float* __restrict__ embed, const int* __restrict__ offs,
                        const int* __restrict__ ssrc, const float* __restrict__ bias1,
                        float* __restrict__ h1, int N) {
    int node = blockIdx.x * (blockDim.x >> 6) + (threadIdx.x >> 6);
    int lane = threadIdx.x & 63;
    if (node >= N) return;
    float2 tot = make_float2(0.f, 0.f);
    for (int r = 0; r < RELS; ++r) {
        int beg = offs[r * N + node];
        int end = offs[r * N + node + 1];
        float2 acc = make_float2(0.f, 0.f);
        for (int e = beg; e < end; ++e) {
            int s = ssrc[e];
            float2 v = *(const float2*)(embed + (size_t)s * H + lane * 2);
            acc.x += v.x; acc.y += v.y;
        }
        float inv = 1.0f / fmaxf((float)(end - beg), 1.0f);
        tot.x += acc.x * inv;
        tot.y += acc.y * inv;
    }
    tot.x = fmaxf(tot.x + bias1[lane * 2],     0.f);
    tot.y = fmaxf(tot.y + bias1[lane * 2 + 1], 0.f);
    *(float2*)(h1 + (size_t)node * H + lane * 2) = tot;
}

// ---------- Layer 2 GEMM: T[r] = A @ W[r], A-tile staged once for all nrel ----------
__global__ __launch_bounds__(256) void k_gemm(const float* __restrict__ A,
                                              const float* __restrict__ W,
                                              float* __restrict__ T, int N, int nrel) {
    __shared__ float As[64 * 132];
    __shared__ float Bs[128 * 64];
    int tid = threadIdx.x;
    int row0 = blockIdx.x * 64;

#pragma unroll
    for (int i = 0; i < 8; ++i) {
        int idx = (tid + i * 256) * 4;
        int rr = idx >> 7, cc = idx & 127;
        int grow = row0 + rr;
        float4 v = make_float4(0.f, 0.f, 0.f, 0.f);
        if (grow < N) v = *(const float4*)(A + (size_t)grow * H + cc);
        *(float4*)(As + rr * 132 + cc) = v;
    }

    for (int r = 0; r < nrel; ++r) {
        __syncthreads();   // As ready (r=0) / previous compute done before Bs overwrite
        const float4* W4 = (const float4*)(W + (size_t)r * H * O);
#pragma unroll
        for (int i = 0; i < 8; ++i) ((float4*)Bs)[tid + i * 256] = W4[tid + i * 256];
        __syncthreads();

        int ty = tid >> 4, tx = tid & 15;
        float acc[4][4] = {};
        for (int k = 0; k < 128; ++k) {
            float av[4];
#pragma unroll
            for (int i = 0; i < 4; ++i) av[i] = As[(ty * 4 + i) * 132 + k];
            float4 b = *(const float4*)(Bs + k * 64 + tx * 4);
#pragma unroll
            for (int i = 0; i < 4; ++i) {
                acc[i][0] += av[i] * b.x;
                acc[i][1] += av[i] * b.y;
                acc[i][2] += av[i] * b.z;
                acc[i][3] += av[i] * b.w;
            }
        }
#pragma unroll
        for (int i = 0; i < 4; ++i) {
            int grow = row0 + ty * 4 + i;
            if (grow < N)
                *(float4*)(T + ((size_t)r * N + grow) * O + tx * 4) =
                    make_float4(acc[i][0], acc[i][1], acc[i][2], acc[i][3]);
        }
    }
}

// ---------- Layer 2 pull ----------
// FUSED: out = bias2 + sum_r mean_r(T_r[src]); else accumulate one relation into out
template <bool FUSED>
__global__ void k_pull2(const float* __restrict__ T, const int* __restrict__ offs,
                        const int* __restrict__ ssrc, const float* __restrict__ bias2,
                        float* __restrict__ out, int N) {
    int node = blockIdx.x * (blockDim.x >> 6) + (threadIdx.x >> 6);
    int lane = threadIdx.x & 63;
    if (node >= N) return;
    if (FUSED) {
        float tot = bias2[lane];
        for (int r = 0; r < RELS; ++r) {
            int beg = offs[r * N + node];
            int end = offs[r * N + node + 1];
            float acc = 0.f;
            for (int e = beg; e < end; ++e) {
                int s = ssrc[e];
                acc += T[((size_t)r * N + s) * O + lane];
            }
            tot += acc / fmaxf((float)(end - beg), 1.0f);
        }
        out[(size_t)node * O + lane] = tot;
    } else {
        int beg = offs[node];
        int end = offs[node + 1];
        float acc = 0.f;
        for (int e = beg; e < end; ++e) {
            int s = ssrc[e];
            acc += T[(size_t)s * O + lane];
        }
        out[(size_t)node * O + lane] += acc / fmaxf((float)(end - beg), 1.0f);
    }
}

__global__ void k_init_out(float* __restrict__ out, const float* __restrict__ bias2, int total) {
    int i = blockIdx.x * blockDim.x + threadIdx.x;
    if (i < total) out[i] = bias2[i & (O - 1)];
}

extern "C" void kernel_launch(void* const* d_in, const int* in_sizes, int n_in,
                              void* d_out, int out_size, void* d_ws, size_t ws_size,
                              hipStream_t stream) {
    const float* embed  = (const float*)d_in[0];
    const float* weight = (const float*)d_in[1];
    const float* bias1  = (const float*)d_in[2];
    const float* bias2  = (const float*)d_in[3];
    const int*   esrc   = (const int*)d_in[4];
    const int*   edst   = (const int*)d_in[5];
    float* out = (float*)d_out;

    const int N = in_sizes[0] / H;
    const int E = in_sizes[4] / RELS;
    const int RN = RELS * N;
    const int RE = RELS * E;

    // workspace layout
    char* p = (char*)d_ws;
    auto alloc = [&](size_t bytes) {
        char* q = p;
        p += (bytes + 255) & ~(size_t)255;
        return q;
    };
    int* cnt    = (int*)alloc((size_t)RN * 4);
    int* offs   = (int*)alloc(((size_t)RN + 1) * 4);
    int* cursor = (int*)alloc((size_t)RN * 4);
    int* bsum   = (int*)alloc(4096);
    int* ssrc   = (int*)alloc((size_t)RE * 4);
    float* h1   = (float*)alloc((size_t)N * H * 4);
    size_t used = (size_t)(p - (char*)d_ws);
    bool fused = (ws_size - used) >= ((size_t)RELS * N * O * 4 + 256);
    float* T = (float*)alloc(fused ? (size_t)RELS * N * O * 4 : (size_t)N * O * 4);

    hipMemsetAsync(cnt, 0, (size_t)RN * 4, stream);

    for (int r = 0; r < RELS; ++r)
        k_hist<<<(E + 255) / 256, 256, 0, stream>>>(edst + (size_t)r * E, cnt + (size_t)r * N, E);

    int nb = (RN + 1023) / 1024;   // 391 for this shape (<= 512)
    k_scan1<<<nb, 256, 0, stream>>>(cnt, offs, bsum, RN);
    k_scan2<<<1, 512, 0, stream>>>(bsum, nb);
    k_scan3<<<(RN + 255) / 256, 256, 0, stream>>>(offs, cursor, bsum, RN, RE);

    for (int r = 0; r < RELS; ++r)
        k_fill<<<(E + 255) / 256, 256, 0, stream>>>(esrc + (size_t)r * E, edst + (size_t)r * E,
                                                    cursor + (size_t)r * N, ssrc, E);

    // Layer 1: fused pull (mean over each relation, sum, bias, relu)
    k_pull1<<<(N + 3) / 4, 256, 0, stream>>>(embed, offs, ssrc, bias1, h1, N);

    if (fused) {
        k_gemm<<<(N + 63) / 64, 256, 0, stream>>>(h1, weight, T, N, RELS);
        k_pull2<true><<<(N + 3) / 4, 256, 0, stream>>>(T, offs, ssrc, bias2, out, N);
    } else {
        k_init_out<<<(N * O + 255) / 256, 256, 0, stream>>>(out, bias2, N * O);
        for (int r = 0; r < RELS; ++r) {
            k_gemm<<<(N + 63) / 64, 256, 0, stream>>>(h1, weight + (size_t)r * H * O, T, N, 1);
            k_pull2<false><<<(N + 3) / 4, 256, 0, stream>>>(T, offs + (size_t)r * N, ssrc,
                                                            bias2, out, N);
        }
    }
}

// Round 3
// 295.763 us; speedup vs baseline: 3.0319x; 1.2146x over previous
//
#include <hip/hip_runtime.h>
#include <hip/hip_bf16.h>

#define H 128
#define O 64
#define RELS 4

typedef short short8 __attribute__((ext_vector_type(8)));
typedef float f32x4 __attribute__((ext_vector_type(4)));

static __device__ __forceinline__ unsigned short f2b(float x) {
    __hip_bfloat16 h = __float2bfloat16(x);           // RNE
    return *reinterpret_cast<unsigned short*>(&h);
}
static __device__ __forceinline__ float b2f(unsigned short b) {
    return __uint_as_float(((unsigned int)b) << 16);  // exact
}

// ---------- CSR construction ----------
__global__ void k_hist(const int* __restrict__ dst, int* __restrict__ cnt,
                       int E, int RE, int N) {
    int i = blockIdx.x * blockDim.x + threadIdx.x;
    if (i < RE) { int r = i / E; atomicAdd(&cnt[r * N + dst[i]], 1); }
}

__global__ void k_scan1(const int* __restrict__ cnt, int* __restrict__ offs,
                        int* __restrict__ bsum, int n) {
    __shared__ int sh[256];
    int t = threadIdx.x;
    int base = blockIdx.x * 1024 + t * 4;
    int4 v = make_int4(0, 0, 0, 0);
    if (base + 3 < n) v = *(const int4*)(cnt + base);
    else {
        if (base < n)     v.x = cnt[base];
        if (base + 1 < n) v.y = cnt[base + 1];
        if (base + 2 < n) v.z = cnt[base + 2];
    }
    int s = v.x + v.y + v.z + v.w;
    sh[t] = s; __syncthreads();
    for (int off = 1; off < 256; off <<= 1) {
        int x = (t >= off) ? sh[t - off] : 0;
        __syncthreads();
        sh[t] += x;
        __syncthreads();
    }
    int incl = sh[t];
    int ex = incl - s;
    if (base < n)     offs[base]     = ex;
    if (base + 1 < n) offs[base + 1] = ex + v.x;
    if (base + 2 < n) offs[base + 2] = ex + v.x + v.y;
    if (base + 3 < n) offs[base + 3] = ex + v.x + v.y + v.z;
    if (t == 255) bsum[blockIdx.x] = incl;
}

__global__ void k_scan2(int* __restrict__ bsum, int nb) {
    __shared__ int sh[512];
    int t = threadIdx.x;
    int s = (t < nb) ? bsum[t] : 0;
    sh[t] = s; __syncthreads();
    for (int off = 1; off < 512; off <<= 1) {
        int x = (t >= off) ? sh[t - off] : 0;
        __syncthreads();
        sh[t] += x;
        __syncthreads();
    }
    if (t < nb) bsum[t] = sh[t] - s;
}

__global__ void k_scan3(int* __restrict__ offs, int* __restrict__ cursor,
                        const int* __restrict__ bsum, int n, int total) {
    int i = blockIdx.x * blockDim.x + threadIdx.x;
    if (i < n) {
        int v = offs[i] + bsum[i >> 10];
        offs[i] = v;
        cursor[i] = v;
    }
    if (i == 0) offs[n] = total;
}

__global__ void k_fill(const int* __restrict__ src, const int* __restrict__ dst,
                       int* __restrict__ cursor, int* __restrict__ ssrc,
                       int E, int RE, int N) {
    int i = blockIdx.x * blockDim.x + threadIdx.x;
    if (i < RE) {
        int r = i / E;
        int pos = atomicAdd(&cursor[r * N + dst[i]], 1);
        ssrc[pos] = src[i];
    }
}

// ---------- dtype prep ----------
// embed f32 -> bf16, float4 in, ushort4 out
__global__ void k_cvt(const float* __restrict__ in, unsigned short* __restrict__ outb, int n4) {
    int i = blockIdx.x * blockDim.x + threadIdx.x;
    if (i >= n4) return;
    float4 v = ((const float4*)in)[i];
    ushort4 o;
    o.x = f2b(v.x); o.y = f2b(v.y); o.z = f2b(v.z); o.w = f2b(v.w);
    ((ushort4*)outb)[i] = o;
}

// WT[r][n][k] = bf16(W[r][k][n])  (RELS*O*H elements)
__global__ void k_wprep(const float* __restrict__ W, unsigned short* __restrict__ WT, int total) {
    int i = blockIdx.x * blockDim.x + threadIdx.x;
    if (i >= total) return;
    int r = i >> 13;            // O*H = 8192
    int n = (i >> 7) & (O - 1);
    int k = i & (H - 1);
    WT[i] = f2b(W[((size_t)r * H + k) * O + n]);
}

// ---------- Layer 1: fused pull + bias + relu, bf16 in / bf16 out ----------
__global__ void k_pull1(const unsigned short* __restrict__ eb, const int* __restrict__ offs,
                        const int* __restrict__ ssrc, const float* __restrict__ bias1,
                        unsigned short* __restrict__ h1, int N) {
    int node = blockIdx.x * (blockDim.x >> 6) + (threadIdx.x >> 6);
    int lane = threadIdx.x & 63;
    if (node >= N) return;
    float sx = 0.f, sy = 0.f;
    for (int r = 0; r < RELS; ++r) {
        int beg = offs[r * N + node];
        int end = offs[r * N + node + 1];
        float ax = 0.f, ay = 0.f;
        for (int e = beg; e < end; ++e) {
            int s = ssrc[e];
            unsigned int u = *(const unsigned int*)(eb + (size_t)s * H + lane * 2);
            ax += __uint_as_float(u << 16);
            ay += __uint_as_float(u & 0xffff0000u);
        }
        float inv = 1.0f / fmaxf((float)(end - beg), 1.0f);
        sx += ax * inv;
        sy += ay * inv;
    }
    sx = fmaxf(sx + bias1[lane * 2],     0.f);
    sy = fmaxf(sy + bias1[lane * 2 + 1], 0.f);
    unsigned int o = (unsigned int)f2b(sx) | ((unsigned int)f2b(sy) << 16);
    *(unsigned int*)(h1 + (size_t)node * H + lane * 2) = o;
}

// ---------- Layer 2 GEMM (MFMA bf16): T[r][N][64] = h1 @ W[r] ----------
// 256 thr = 4 waves, 128 rows/block (32/wave). A-frags from global (reused 16x),
// B-frags from WT (L1/L2-hot). C -> bf16 via wave-private LDS transpose.
__global__ __launch_bounds__(256) void k_gemm(const unsigned short* __restrict__ h1,
                                              const unsigned short* __restrict__ WT,
                                              unsigned short* __restrict__ T, int N) {
    __shared__ __align__(16) unsigned short st[4][32][72];   // pad 64->72 vs bank conflicts
    int tid = threadIdx.x, w = tid >> 6, l = tid & 63;
    int row0 = blockIdx.x * 128 + w * 32;
    int rA = l & 15, kb = (l >> 4) * 8;

    short8 af[2][4];
#pragma unroll
    for (int mf = 0; mf < 2; ++mf)
#pragma unroll
        for (int kk = 0; kk < 4; ++kk) {
            int row = row0 + mf * 16 + rA;
            short8 v = {0, 0, 0, 0, 0, 0, 0, 0};
            if (row < N) v = *(const short8*)(h1 + (size_t)row * H + kk * 32 + kb);
            af[mf][kk] = v;
        }

    for (int r = 0; r < RELS; ++r) {
        f32x4 z = {0.f, 0.f, 0.f, 0.f};
        f32x4 acc[2][4];
#pragma unroll
        for (int mf = 0; mf < 2; ++mf)
#pragma unroll
            for (int nt = 0; nt < 4; ++nt) acc[mf][nt] = z;

#pragma unroll
        for (int nt = 0; nt < 4; ++nt) {
            short8 bf[4];
#pragma unroll
            for (int kk = 0; kk < 4; ++kk)
                bf[kk] = *(const short8*)(WT + (((size_t)r * O + nt * 16 + rA) * H + kk * 32 + kb));
#pragma unroll
            for (int kk = 0; kk < 4; ++kk)
#pragma unroll
                for (int mf = 0; mf < 2; ++mf)
                    acc[mf][nt] = __builtin_amdgcn_mfma_f32_16x16x32_bf16(
                        af[mf][kk], bf[kk], acc[mf][nt], 0, 0, 0);
        }

        // C layout: col = l&15, row = (l>>4)*4 + j  -> LDS -> row-major bf16 store
#pragma unroll
        for (int mf = 0; mf < 2; ++mf)
#pragma unroll
            for (int nt = 0; nt < 4; ++nt)
#pragma unroll
                for (int j = 0; j < 4; ++j)
                    st[w][mf * 16 + (l >> 4) * 4 + j][nt * 16 + (l & 15)] = f2b(acc[mf][nt][j]);

#pragma unroll
        for (int i = 0; i < 4; ++i) {
            int rr = i * 8 + (l >> 3);
            uint4 v = *(const uint4*)&st[w][rr][(l & 7) * 8];
            int grow = row0 + rr;
            if (grow < N)
                *(uint4*)(T + ((size_t)r * N + grow) * O + (l & 7) * 8) = v;
        }
    }
}

// ---------- Layer 2 pull: out = bias2 + sum_r mean_r(T_r[src]) ----------
__global__ void k_pull2(const unsigned short* __restrict__ T, const int* __restrict__ offs,
                        const int* __restrict__ ssrc, const float* __restrict__ bias2,
                        float* __restrict__ out, int N) {
    int node = blockIdx.x * (blockDim.x >> 6) + (threadIdx.x >> 6);
    int lane = threadIdx.x & 63;
    if (node >= N) return;
    float tot = bias2[lane];
    for (int r = 0; r < RELS; ++r) {
        int beg = offs[r * N + node];
        int end = offs[r * N + node + 1];
        float acc = 0.f;
        for (int e = beg; e < end; ++e) {
            int s = ssrc[e];
            acc += b2f(T[((size_t)r * N + s) * O + lane]);
        }
        tot += acc / fmaxf((float)(end - beg), 1.0f);
    }
    out[(size_t)node * O + lane] = tot;
}

extern "C" void kernel_launch(void* const* d_in, const int* in_sizes, int n_in,
                              void* d_out, int out_size, void* d_ws, size_t ws_size,
                              hipStream_t stream) {
    const float* embed  = (const float*)d_in[0];
    const float* weight = (const float*)d_in[1];
    const float* bias1  = (const float*)d_in[2];
    const float* bias2  = (const float*)d_in[3];
    const int*   esrc   = (const int*)d_in[4];
    const int*   edst   = (const int*)d_in[5];
    float* out = (float*)d_out;

    const int N = in_sizes[0] / H;
    const int E = in_sizes[4] / RELS;
    const int RN = RELS * N;
    const int RE = RELS * E;

    char* p = (char*)d_ws;
    auto alloc = [&](size_t bytes) {
        char* q = p;
        p += (bytes + 255) & ~(size_t)255;
        return q;
    };
    int* cnt    = (int*)alloc((size_t)RN * 4);
    int* offs   = (int*)alloc(((size_t)RN + 1) * 4);
    int* cursor = (int*)alloc((size_t)RN * 4);
    int* bsum   = (int*)alloc(4096);
    int* ssrc   = (int*)alloc((size_t)RE * 4);
    unsigned short* eb  = (unsigned short*)alloc((size_t)N * H * 2);
    unsigned short* h1  = (unsigned short*)alloc((size_t)N * H * 2);
    unsigned short* WT  = (unsigned short*)alloc((size_t)RELS * O * H * 2);
    unsigned short* T   = (unsigned short*)alloc((size_t)RELS * N * O * 2);
    // total ~110 MB

    hipMemsetAsync(cnt, 0, (size_t)RN * 4, stream);

    k_hist<<<(RE + 255) / 256, 256, 0, stream>>>(edst, cnt, E, RE, N);

    int nb = (RN + 1023) / 1024;
    k_scan1<<<nb, 256, 0, stream>>>(cnt, offs, bsum, RN);
    k_scan2<<<1, 512, 0, stream>>>(bsum, nb);
    k_scan3<<<(RN + 255) / 256, 256, 0, stream>>>(offs, cursor, bsum, RN, RE);

    k_fill<<<(RE + 255) / 256, 256, 0, stream>>>(esrc, edst, cursor, ssrc, E, RE, N);

    k_cvt<<<((N * H / 4) + 255) / 256, 256, 0, stream>>>(embed, eb, N * H / 4);
    k_wprep<<<(RELS * O * H + 255) / 256, 256, 0, stream>>>(weight, WT, RELS * O * H);

    k_pull1<<<(N + 3) / 4, 256, 0, stream>>>(eb, offs, ssrc, bias1, h1, N);

    k_gemm<<<(N + 127) / 128, 256, 0, stream>>>(h1, WT, T, N);

    k_pull2<<<(N + 3) / 4, 256, 0, stream>>>(T, offs, ssrc, bias2, out, N);
}

// Round 4
// 213.452 us; speedup vs baseline: 4.2010x; 1.3856x over previous
//
#include <hip/hip_runtime.h>
#include <hip/hip_bf16.h>

#define H 128
#define O 64
#define RELS 4

typedef short short8 __attribute__((ext_vector_type(8)));
typedef float f32x4 __attribute__((ext_vector_type(4)));

static __device__ __forceinline__ unsigned short f2b(float x) {
    __hip_bfloat16 h = __float2bfloat16(x);           // RNE
    return *reinterpret_cast<unsigned short*>(&h);
}
static __device__ __forceinline__ float blo(unsigned u) { return __uint_as_float(u << 16); }
static __device__ __forceinline__ float bhi(unsigned u) { return __uint_as_float(u & 0xffff0000u); }

// ---------- CSR construction (node-major, all relations contiguous per node) ----------
__global__ void k_hist(const int* __restrict__ dst, int* __restrict__ cnt,
                       int E, int RE, int N) {
    int i = blockIdx.x * blockDim.x + threadIdx.x;
    if (i < RE) { int r = i / E; atomicAdd(&cnt[r * N + dst[i]], 1); }
}

// totdeg[node] = sum_r cnt[r*N+node]   (written into cursor[0..N) as scratch)
__global__ void k_nodecnt(const int* __restrict__ cnt, int* __restrict__ totdeg, int N) {
    int i = blockIdx.x * blockDim.x + threadIdx.x;
    if (i < N) totdeg[i] = cnt[i] + cnt[N + i] + cnt[2 * N + i] + cnt[3 * N + i];
}

__global__ void k_scan1(const int* __restrict__ cnt, int* __restrict__ offs,
                        int* __restrict__ bsum, int n) {
    __shared__ int sh[256];
    int t = threadIdx.x;
    int base = blockIdx.x * 1024 + t * 4;
    int4 v = make_int4(0, 0, 0, 0);
    if (base + 3 < n) v = *(const int4*)(cnt + base);
    else {
        if (base < n)     v.x = cnt[base];
        if (base + 1 < n) v.y = cnt[base + 1];
        if (base + 2 < n) v.z = cnt[base + 2];
    }
    int s = v.x + v.y + v.z + v.w;
    sh[t] = s; __syncthreads();
    for (int off = 1; off < 256; off <<= 1) {
        int x = (t >= off) ? sh[t - off] : 0;
        __syncthreads();
        sh[t] += x;
        __syncthreads();
    }
    int incl = sh[t];
    int ex = incl - s;
    if (base < n)     offs[base]     = ex;
    if (base + 1 < n) offs[base + 1] = ex + v.x;
    if (base + 2 < n) offs[base + 2] = ex + v.x + v.y;
    if (base + 3 < n) offs[base + 3] = ex + v.x + v.y + v.z;
    if (t == 255) bsum[blockIdx.x] = incl;
}

__global__ void k_scan2(int* __restrict__ bsum, int nb) {
    __shared__ int sh[512];
    int t = threadIdx.x;
    int s = (t < nb) ? bsum[t] : 0;
    sh[t] = s; __syncthreads();
    for (int off = 1; off < 512; off <<= 1) {
        int x = (t >= off) ? sh[t - off] : 0;
        __syncthreads();
        sh[t] += x;
        __syncthreads();
    }
    if (t < nb) bsum[t] = sh[t] - s;
}

__global__ void k_scan3(int* __restrict__ offs, const int* __restrict__ bsum, int n, int total) {
    int i = blockIdx.x * blockDim.x + threadIdx.x;
    if (i < n) offs[i] += bsum[i >> 10];
    if (i == 0) offs[n] = total;
}

// cursor[r*N+node] = offs2[node] + prefix of cnt over relations
__global__ void k_cursor(const int* __restrict__ cnt, const int* __restrict__ offs2,
                         int* __restrict__ cursor, int N) {
    int i = blockIdx.x * blockDim.x + threadIdx.x;
    if (i >= N) return;
    int base = offs2[i];
    int c0 = cnt[i], c1 = cnt[N + i], c2 = cnt[2 * N + i];
    cursor[i]         = base;
    cursor[N + i]     = base + c0;
    cursor[2 * N + i] = base + c0 + c1;
    cursor[3 * N + i] = base + c0 + c1 + c2;
}

// per edge: record {rowidx = r*N+src, w = 1/deg_r(dst)} at CSR position
__global__ void k_fill(const int* __restrict__ src, const int* __restrict__ dst,
                       const int* __restrict__ cnt, int* __restrict__ cursor,
                       uint2* __restrict__ ue, int E, int RE, int N) {
    int i = blockIdx.x * blockDim.x + threadIdx.x;
    if (i >= RE) return;
    int r = i / E;
    int d = dst[i];
    int pos = atomicAdd(&cursor[r * N + d], 1);
    float w = 1.0f / (float)max(cnt[r * N + d], 1);
    ue[pos] = make_uint2((unsigned)(r * N + src[i]), __float_as_uint(w));
}

// ---------- dtype prep ----------
__global__ void k_cvt(const float* __restrict__ in, unsigned short* __restrict__ outb, int n4) {
    int i = blockIdx.x * blockDim.x + threadIdx.x;
    if (i >= n4) return;
    float4 v = ((const float4*)in)[i];
    ushort4 o;
    o.x = f2b(v.x); o.y = f2b(v.y); o.z = f2b(v.z); o.w = f2b(v.w);
    ((ushort4*)outb)[i] = o;
}

__global__ void k_wprep(const float* __restrict__ W, unsigned short* __restrict__ WT, int total) {
    int i = blockIdx.x * blockDim.x + threadIdx.x;
    if (i >= total) return;
    int r = i >> 13;            // O*H = 8192
    int n = (i >> 7) & (O - 1);
    int k = i & (H - 1);
    WT[i] = f2b(W[((size_t)r * H + k) * O + n]);
}

// ---------- Layer 1: flat weighted pull + bias + relu ----------
// 1 node/wave; lanes 0-31 = edge e, lanes 32-63 = edge e+1; lane covers 4 features (8B).
__global__ void k_pull1(const unsigned short* __restrict__ eb, const int* __restrict__ offs2,
                        const uint2* __restrict__ ue, const float* __restrict__ bias1,
                        unsigned short* __restrict__ h1, int N) {
    int node = blockIdx.x * (blockDim.x >> 6) + (threadIdx.x >> 6);
    if (node >= N) return;
    int lane = threadIdx.x & 63;
    int half = lane >> 5, fl = lane & 31;
    int beg = offs2[node], end = offs2[node + 1];

    float a0 = 0.f, a1 = 0.f, a2 = 0.f, a3 = 0.f;   // set A (unroll slot 0)
    float c0 = 0.f, c1 = 0.f, c2 = 0.f, c3 = 0.f;   // set B (unroll slot 1)
    unsigned N1 = (unsigned)N, N2 = (unsigned)(2 * N);

    int e = beg;
    for (; e + 4 <= end; e += 4) {
        uint2 p0 = ue[e + half];
        uint2 p1 = ue[e + 2 + half];
        unsigned s0 = p0.x; if (s0 >= N2) s0 -= N2; if (s0 >= N1) s0 -= N1;
        unsigned s1 = p1.x; if (s1 >= N2) s1 -= N2; if (s1 >= N1) s1 -= N1;
        float w0 = __uint_as_float(p0.y), w1 = __uint_as_float(p1.y);
        uint2 u0 = *(const uint2*)(eb + (size_t)s0 * H + fl * 4);
        uint2 u1 = *(const uint2*)(eb + (size_t)s1 * H + fl * 4);
        a0 += w0 * blo(u0.x); a1 += w0 * bhi(u0.x); a2 += w0 * blo(u0.y); a3 += w0 * bhi(u0.y);
        c0 += w1 * blo(u1.x); c1 += w1 * bhi(u1.x); c2 += w1 * blo(u1.y); c3 += w1 * bhi(u1.y);
    }
    for (; e + 2 <= end; e += 2) {
        uint2 p0 = ue[e + half];
        unsigned s0 = p0.x; if (s0 >= N2) s0 -= N2; if (s0 >= N1) s0 -= N1;
        float w0 = __uint_as_float(p0.y);
        uint2 u0 = *(const uint2*)(eb + (size_t)s0 * H + fl * 4);
        a0 += w0 * blo(u0.x); a1 += w0 * bhi(u0.x); a2 += w0 * blo(u0.y); a3 += w0 * bhi(u0.y);
    }
    if (e < end && half == 0) {
        uint2 p0 = ue[e];
        unsigned s0 = p0.x; if (s0 >= N2) s0 -= N2; if (s0 >= N1) s0 -= N1;
        float w0 = __uint_as_float(p0.y);
        uint2 u0 = *(const uint2*)(eb + (size_t)s0 * H + fl * 4);
        a0 += w0 * blo(u0.x); a1 += w0 * bhi(u0.x); a2 += w0 * blo(u0.y); a3 += w0 * bhi(u0.y);
    }

    float f0 = a0 + c0, f1 = a1 + c1, f2 = a2 + c2, f3 = a3 + c3;
    f0 += __shfl_xor(f0, 32);
    f1 += __shfl_xor(f1, 32);
    f2 += __shfl_xor(f2, 32);
    f3 += __shfl_xor(f3, 32);
    if (half == 0) {
        f0 = fmaxf(f0 + bias1[fl * 4 + 0], 0.f);
        f1 = fmaxf(f1 + bias1[fl * 4 + 1], 0.f);
        f2 = fmaxf(f2 + bias1[fl * 4 + 2], 0.f);
        f3 = fmaxf(f3 + bias1[fl * 4 + 3], 0.f);
        uint2 o;
        o.x = (unsigned)f2b(f0) | ((unsigned)f2b(f1) << 16);
        o.y = (unsigned)f2b(f2) | ((unsigned)f2b(f3) << 16);
        *(uint2*)(h1 + (size_t)node * H + fl * 4) = o;
    }
}

// ---------- Layer 2 GEMM (MFMA bf16): T[r][N][64] = h1 @ W[r] ----------
__global__ __launch_bounds__(256) void k_gemm(const unsigned short* __restrict__ h1,
                                              const unsigned short* __restrict__ WT,
                                              unsigned short* __restrict__ T, int N) {
    __shared__ __align__(16) unsigned short st[4][32][72];
    int tid = threadIdx.x, w = tid >> 6, l = tid & 63;
    int row0 = blockIdx.x * 128 + w * 32;
    int rA = l & 15, kb = (l >> 4) * 8;

    short8 af[2][4];
#pragma unroll
    for (int mf = 0; mf < 2; ++mf)
#pragma unroll
        for (int kk = 0; kk < 4; ++kk) {
            int row = row0 + mf * 16 + rA;
            short8 v = {0, 0, 0, 0, 0, 0, 0, 0};
            if (row < N) v = *(const short8*)(h1 + (size_t)row * H + kk * 32 + kb);
            af[mf][kk] = v;
        }

    for (int r = 0; r < RELS; ++r) {
        f32x4 z = {0.f, 0.f, 0.f, 0.f};
        f32x4 acc[2][4];
#pragma unroll
        for (int mf = 0; mf < 2; ++mf)
#pragma unroll
            for (int nt = 0; nt < 4; ++nt) acc[mf][nt] = z;

#pragma unroll
        for (int nt = 0; nt < 4; ++nt) {
            short8 bf[4];
#pragma unroll
            for (int kk = 0; kk < 4; ++kk)
                bf[kk] = *(const short8*)(WT + (((size_t)r * O + nt * 16 + rA) * H + kk * 32 + kb));
#pragma unroll
            for (int kk = 0; kk < 4; ++kk)
#pragma unroll
                for (int mf = 0; mf < 2; ++mf)
                    acc[mf][nt] = __builtin_amdgcn_mfma_f32_16x16x32_bf16(
                        af[mf][kk], bf[kk], acc[mf][nt], 0, 0, 0);
        }

#pragma unroll
        for (int mf = 0; mf < 2; ++mf)
#pragma unroll
            for (int nt = 0; nt < 4; ++nt)
#pragma unroll
                for (int j = 0; j < 4; ++j)
                    st[w][mf * 16 + (l >> 4) * 4 + j][nt * 16 + (l & 15)] = f2b(acc[mf][nt][j]);

#pragma unroll
        for (int i = 0; i < 4; ++i) {
            int rr = i * 8 + (l >> 3);
            uint4 v = *(const uint4*)&st[w][rr][(l & 7) * 8];
            int grow = row0 + rr;
            if (grow < N)
                *(uint4*)(T + ((size_t)r * N + grow) * O + (l & 7) * 8) = v;
        }
    }
}

// ---------- Layer 2: flat weighted pull + bias ----------
// 1 node/wave; lanes 0-31 = edge e, lanes 32-63 = edge e+1; lane covers 2 features (4B).
__global__ void k_pull2(const unsigned short* __restrict__ T, const int* __restrict__ offs2,
                        const uint2* __restrict__ ue, const float* __restrict__ bias2,
                        float* __restrict__ out, int N) {
    int node = blockIdx.x * (blockDim.x >> 6) + (threadIdx.x >> 6);
    if (node >= N) return;
    int lane = threadIdx.x & 63;
    int half = lane >> 5, fl = lane & 31;
    int beg = offs2[node], end = offs2[node + 1];

    float ax = 0.f, ay = 0.f, cx = 0.f, cy = 0.f;

    int e = beg;
    for (; e + 4 <= end; e += 4) {
        uint2 p0 = ue[e + half];
        uint2 p1 = ue[e + 2 + half];
        float w0 = __uint_as_float(p0.y), w1 = __uint_as_float(p1.y);
        unsigned u0 = *(const unsigned*)(T + (size_t)p0.x * O + fl * 2);
        unsigned u1 = *(const unsigned*)(T + (size_t)p1.x * O + fl * 2);
        ax += w0 * blo(u0); ay += w0 * bhi(u0);
        cx += w1 * blo(u1); cy += w1 * bhi(u1);
    }
    for (; e + 2 <= end; e += 2) {
        uint2 p0 = ue[e + half];
        float w0 = __uint_as_float(p0.y);
        unsigned u0 = *(const unsigned*)(T + (size_t)p0.x * O + fl * 2);
        ax += w0 * blo(u0); ay += w0 * bhi(u0);
    }
    if (e < end && half == 0) {
        uint2 p0 = ue[e];
        float w0 = __uint_as_float(p0.y);
        unsigned u0 = *(const unsigned*)(T + (size_t)p0.x * O + fl * 2);
        ax += w0 * blo(u0); ay += w0 * bhi(u0);
    }

    float fx = ax + cx, fy = ay + cy;
    fx += __shfl_xor(fx, 32);
    fy += __shfl_xor(fy, 32);
    if (half == 0) {
        float2 v;
        v.x = fx + bias2[fl * 2 + 0];
        v.y = fy + bias2[fl * 2 + 1];
        *(float2*)(out + (size_t)node * O + fl * 2) = v;
    }
}

extern "C" void kernel_launch(void* const* d_in, const int* in_sizes, int n_in,
                              void* d_out, int out_size, void* d_ws, size_t ws_size,
                              hipStream_t stream) {
    const float* embed  = (const float*)d_in[0];
    const float* weight = (const float*)d_in[1];
    const float* bias1  = (const float*)d_in[2];
    const float* bias2  = (const float*)d_in[3];
    const int*   esrc   = (const int*)d_in[4];
    const int*   edst   = (const int*)d_in[5];
    float* out = (float*)d_out;

    const int N = in_sizes[0] / H;
    const int E = in_sizes[4] / RELS;
    const int RN = RELS * N;
    const int RE = RELS * E;

    char* p = (char*)d_ws;
    auto alloc = [&](size_t bytes) {
        char* q = p;
        p += (bytes + 255) & ~(size_t)255;
        return q;
    };
    int* cnt    = (int*)alloc((size_t)RN * 4);
    int* offs2  = (int*)alloc(((size_t)N + 1) * 4);
    int* cursor = (int*)alloc((size_t)RN * 4);   // first N ints double as totdeg scratch
    int* bsum   = (int*)alloc(4096);
    uint2* ue   = (uint2*)alloc((size_t)RE * 8);
    unsigned short* eb  = (unsigned short*)alloc((size_t)N * H * 2);
    unsigned short* h1  = (unsigned short*)alloc((size_t)N * H * 2);
    unsigned short* WT  = (unsigned short*)alloc((size_t)RELS * O * H * 2);
    unsigned short* T   = (unsigned short*)alloc((size_t)RELS * N * O * 2);

    hipMemsetAsync(cnt, 0, (size_t)RN * 4, stream);

    k_hist<<<(RE + 255) / 256, 256, 0, stream>>>(edst, cnt, E, RE, N);
    k_nodecnt<<<(N + 255) / 256, 256, 0, stream>>>(cnt, cursor, N);   // cursor[:N] = totdeg

    int nb = (N + 1023) / 1024;
    k_scan1<<<nb, 256, 0, stream>>>(cursor, offs2, bsum, N);
    k_scan2<<<1, 512, 0, stream>>>(bsum, nb);
    k_scan3<<<(N + 255) / 256, 256, 0, stream>>>(offs2, bsum, N, RE);
    k_cursor<<<(N + 255) / 256, 256, 0, stream>>>(cnt, offs2, cursor, N);

    k_fill<<<(RE + 255) / 256, 256, 0, stream>>>(esrc, edst, cnt, cursor, ue, E, RE, N);

    k_cvt<<<((N * H / 4) + 255) / 256, 256, 0, stream>>>(embed, eb, N * H / 4);
    k_wprep<<<(RELS * O * H + 255) / 256, 256, 0, stream>>>(weight, WT, RELS * O * H);

    k_pull1<<<(N + 3) / 4, 256, 0, stream>>>(eb, offs2, ue, bias1, h1, N);

    k_gemm<<<(N + 127) / 128, 256, 0, stream>>>(h1, WT, T, N);

    k_pull2<<<(N + 3) / 4, 256, 0, stream>>>(T, offs2, ue, bias2, out, N);
}

// Round 6
// 176.429 us; speedup vs baseline: 5.0826x; 1.2098x over previous
//
#include <hip/hip_runtime.h>
#include <hip/hip_bf16.h>

#define H 128
#define O 64
#define RELS 4

typedef short short8 __attribute__((ext_vector_type(8)));
typedef float f32x4 __attribute__((ext_vector_type(4)));

static __device__ __forceinline__ unsigned short f2b(float x) {
    __hip_bfloat16 h = __float2bfloat16(x);           // RNE
    return *reinterpret_cast<unsigned short*>(&h);
}
static __device__ __forceinline__ float blo(unsigned u) { return __uint_as_float(u << 16); }
static __device__ __forceinline__ float bhi(unsigned u) { return __uint_as_float(u & 0xffff0000u); }

// NOTE: parameter names must not collide with vector member names (.x/.y/.z/.w)
#define ACC8(acc, uv, wt)                                           \
    acc[0] += (wt) * blo(uv.x); acc[1] += (wt) * bhi(uv.x);         \
    acc[2] += (wt) * blo(uv.y); acc[3] += (wt) * bhi(uv.y);         \
    acc[4] += (wt) * blo(uv.z); acc[5] += (wt) * bhi(uv.z);         \
    acc[6] += (wt) * blo(uv.w); acc[7] += (wt) * bhi(uv.w);

// ---------- fused prep: embed->bf16, W->WT bf16 transposed, dst histogram ----------
__global__ void k_prep(const float* __restrict__ embed, unsigned short* __restrict__ eb,
                       const float* __restrict__ W, unsigned short* __restrict__ WT,
                       const int* __restrict__ dst, int* __restrict__ cnt,
                       int n4, int wtot, int E, int RE, int N, int b_cvt, int b_w) {
    int b = blockIdx.x;
    if (b < b_cvt) {
        int i = b * 256 + threadIdx.x;
        if (i < n4) {
            float4 v = ((const float4*)embed)[i];
            ushort4 o;
            o.x = f2b(v.x); o.y = f2b(v.y); o.z = f2b(v.z); o.w = f2b(v.w);
            ((ushort4*)eb)[i] = o;
        }
    } else if (b < b_cvt + b_w) {
        int i = (b - b_cvt) * 256 + threadIdx.x;
        if (i < wtot) {
            int r = i >> 13;            // O*H = 8192
            int n = (i >> 7) & (O - 1);
            int k = i & (H - 1);
            WT[i] = f2b(W[((size_t)r * H + k) * O + n]);
        }
    } else {
        int i = (b - b_cvt - b_w) * 256 + threadIdx.x;
        if (i < RE) { int r = i / E; atomicAdd(&cnt[r * N + dst[i]], 1); }
    }
}

// ---------- scan1 with fused per-node total (totdeg = sum_r cnt[r*N+i]) ----------
__global__ void k_scan1(const int* __restrict__ cnt, int* __restrict__ offs,
                        int* __restrict__ bsum, int n, int N_) {
    __shared__ int sh[256];
    int t = threadIdx.x;
    int base = blockIdx.x * 1024 + t * 4;
    int4 v = make_int4(0, 0, 0, 0);
    if (base + 3 < n && (N_ & 3) == 0) {
#pragma unroll
        for (int r = 0; r < RELS; ++r) {
            int4 c = *(const int4*)(cnt + (size_t)r * N_ + base);
            v.x += c.x; v.y += c.y; v.z += c.z; v.w += c.w;
        }
    } else {
        for (int j = 0; j < 4; ++j) {
            int i = base + j;
            if (i < n) {
                int s = 0;
                for (int r = 0; r < RELS; ++r) s += cnt[(size_t)r * N_ + i];
                (&v.x)[j] = s;
            }
        }
    }
    int s = v.x + v.y + v.z + v.w;
    sh[t] = s; __syncthreads();
    for (int off = 1; off < 256; off <<= 1) {
        int x = (t >= off) ? sh[t - off] : 0;
        __syncthreads();
        sh[t] += x;
        __syncthreads();
    }
    int incl = sh[t];
    int ex = incl - s;
    if (base < n)     offs[base]     = ex;
    if (base + 1 < n) offs[base + 1] = ex + v.x;
    if (base + 2 < n) offs[base + 2] = ex + v.x + v.y;
    if (base + 3 < n) offs[base + 3] = ex + v.x + v.y + v.z;
    if (t == 255) bsum[blockIdx.x] = incl;
}

__global__ void k_scan2(int* __restrict__ bsum, int nb) {
    __shared__ int sh[512];
    int t = threadIdx.x;
    int s = (t < nb) ? bsum[t] : 0;
    sh[t] = s; __syncthreads();
    for (int off = 1; off < 512; off <<= 1) {
        int x = (t >= off) ? sh[t - off] : 0;
        __syncthreads();
        sh[t] += x;
        __syncthreads();
    }
    if (t < nb) bsum[t] = sh[t] - s;
}

// finalize offs + build per-(rel,node) cursors
__global__ void k_scan3c(int* __restrict__ offs, const int* __restrict__ bsum,
                         const int* __restrict__ cnt, int* __restrict__ cursor,
                         int n, int total, int N_) {
    int i = blockIdx.x * blockDim.x + threadIdx.x;
    if (i < n) {
        int off = offs[i] + bsum[i >> 10];
        offs[i] = off;
        int c0 = cnt[i], c1 = cnt[N_ + i], c2 = cnt[2 * N_ + i];
        cursor[i]          = off;
        cursor[N_ + i]     = off + c0;
        cursor[2 * N_ + i] = off + c0 + c1;
        cursor[3 * N_ + i] = off + c0 + c1 + c2;
    }
    if (i == 0) offs[n] = total;
}

// per edge: record {rowidx = r*N+src, w = 1/deg_r(dst)} at CSR position
__global__ void k_fill(const int* __restrict__ src, const int* __restrict__ dst,
                       const int* __restrict__ cnt, int* __restrict__ cursor,
                       uint2* __restrict__ ue, int E, int RE, int N) {
    int i = blockIdx.x * blockDim.x + threadIdx.x;
    if (i >= RE) return;
    int r = i / E;
    int d = dst[i];
    int pos = atomicAdd(&cursor[r * N + d], 1);
    float w = 1.0f / (float)max(cnt[r * N + d], 1);
    ue[pos] = make_uint2((unsigned)(r * N + src[i]), __float_as_uint(w));
}

// ---------- Layer 1: 16 lanes per node (4 nodes/wave), uint4 gathers, unroll 2 ----------
__global__ void k_pull1(const unsigned short* __restrict__ eb, const int* __restrict__ offs2,
                        const uint2* __restrict__ ue, const float* __restrict__ bias1,
                        unsigned short* __restrict__ h1, int N) {
    int node = blockIdx.x * 16 + (threadIdx.x >> 4);
    if (node >= N) return;
    int q = threadIdx.x & 15;
    int beg = offs2[node], end = offs2[node + 1];
    unsigned N1 = (unsigned)N, N2 = (unsigned)(2 * N);

    float a[8] = {0.f, 0.f, 0.f, 0.f, 0.f, 0.f, 0.f, 0.f};
    float c[8] = {0.f, 0.f, 0.f, 0.f, 0.f, 0.f, 0.f, 0.f};

    int e = beg;
    for (; e + 2 <= end; e += 2) {
        uint2 p0 = ue[e], p1 = ue[e + 1];
        unsigned s0 = p0.x; if (s0 >= N2) s0 -= N2; if (s0 >= N1) s0 -= N1;
        unsigned s1 = p1.x; if (s1 >= N2) s1 -= N2; if (s1 >= N1) s1 -= N1;
        float w0 = __uint_as_float(p0.y), w1 = __uint_as_float(p1.y);
        uint4 u0 = *(const uint4*)(eb + (size_t)s0 * H + q * 8);
        uint4 u1 = *(const uint4*)(eb + (size_t)s1 * H + q * 8);
        ACC8(a, u0, w0);
        ACC8(c, u1, w1);
    }
    if (e < end) {
        uint2 p0 = ue[e];
        unsigned s0 = p0.x; if (s0 >= N2) s0 -= N2; if (s0 >= N1) s0 -= N1;
        float w0 = __uint_as_float(p0.y);
        uint4 u0 = *(const uint4*)(eb + (size_t)s0 * H + q * 8);
        ACC8(a, u0, w0);
    }

    float4 b0 = *(const float4*)(bias1 + q * 8);
    float4 b1 = *(const float4*)(bias1 + q * 8 + 4);
    float f0 = fmaxf(a[0] + c[0] + b0.x, 0.f);
    float f1 = fmaxf(a[1] + c[1] + b0.y, 0.f);
    float f2 = fmaxf(a[2] + c[2] + b0.z, 0.f);
    float f3 = fmaxf(a[3] + c[3] + b0.w, 0.f);
    float f4 = fmaxf(a[4] + c[4] + b1.x, 0.f);
    float f5 = fmaxf(a[5] + c[5] + b1.y, 0.f);
    float f6 = fmaxf(a[6] + c[6] + b1.z, 0.f);
    float f7 = fmaxf(a[7] + c[7] + b1.w, 0.f);
    uint4 o;
    o.x = (unsigned)f2b(f0) | ((unsigned)f2b(f1) << 16);
    o.y = (unsigned)f2b(f2) | ((unsigned)f2b(f3) << 16);
    o.z = (unsigned)f2b(f4) | ((unsigned)f2b(f5) << 16);
    o.w = (unsigned)f2b(f6) | ((unsigned)f2b(f7) << 16);
    *(uint4*)(h1 + (size_t)node * H + q * 8) = o;
}

// ---------- Layer 2 GEMM (MFMA bf16): T[r][N][64] = h1 @ W[r] ----------
__global__ __launch_bounds__(256) void k_gemm(const unsigned short* __restrict__ h1,
                                              const unsigned short* __restrict__ WT,
                                              unsigned short* __restrict__ T, int N) {
    __shared__ __align__(16) unsigned short st[4][32][72];
    int tid = threadIdx.x, w = tid >> 6, l = tid & 63;
    int row0 = blockIdx.x * 128 + w * 32;
    int rA = l & 15, kb = (l >> 4) * 8;

    short8 af[2][4];
#pragma unroll
    for (int mf = 0; mf < 2; ++mf)
#pragma unroll
        for (int kk = 0; kk < 4; ++kk) {
            int row = row0 + mf * 16 + rA;
            short8 v = {0, 0, 0, 0, 0, 0, 0, 0};
            if (row < N) v = *(const short8*)(h1 + (size_t)row * H + kk * 32 + kb);
            af[mf][kk] = v;
        }

    for (int r = 0; r < RELS; ++r) {
        f32x4 z = {0.f, 0.f, 0.f, 0.f};
        f32x4 acc[2][4];
#pragma unroll
        for (int mf = 0; mf < 2; ++mf)
#pragma unroll
            for (int nt = 0; nt < 4; ++nt) acc[mf][nt] = z;

#pragma unroll
        for (int nt = 0; nt < 4; ++nt) {
            short8 bf[4];
#pragma unroll
            for (int kk = 0; kk < 4; ++kk)
                bf[kk] = *(const short8*)(WT + (((size_t)r * O + nt * 16 + rA) * H + kk * 32 + kb));
#pragma unroll
            for (int kk = 0; kk < 4; ++kk)
#pragma unroll
                for (int mf = 0; mf < 2; ++mf)
                    acc[mf][nt] = __builtin_amdgcn_mfma_f32_16x16x32_bf16(
                        af[mf][kk], bf[kk], acc[mf][nt], 0, 0, 0);
        }

#pragma unroll
        for (int mf = 0; mf < 2; ++mf)
#pragma unroll
            for (int nt = 0; nt < 4; ++nt)
#pragma unroll
                for (int j = 0; j < 4; ++j)
                    st[w][mf * 16 + (l >> 4) * 4 + j][nt * 16 + (l & 15)] = f2b(acc[mf][nt][j]);

#pragma unroll
        for (int i = 0; i < 4; ++i) {
            int rr = i * 8 + (l >> 3);
            uint4 v = *(const uint4*)&st[w][rr][(l & 7) * 8];
            int grow = row0 + rr;
            if (grow < N)
                *(uint4*)(T + ((size_t)r * N + grow) * O + (l & 7) * 8) = v;
        }
    }
}

// ---------- Layer 2: 8 lanes per node (8 nodes/wave), uint4 gathers, unroll 2 ----------
__global__ void k_pull2(const unsigned short* __restrict__ T, const int* __restrict__ offs2,
                        const uint2* __restrict__ ue, const float* __restrict__ bias2,
                        float* __restrict__ out, int N) {
    int node = blockIdx.x * 32 + (threadIdx.x >> 3);
    if (node >= N) return;
    int o = threadIdx.x & 7;
    int beg = offs2[node], end = offs2[node + 1];

    float a[8] = {0.f, 0.f, 0.f, 0.f, 0.f, 0.f, 0.f, 0.f};
    float c[8] = {0.f, 0.f, 0.f, 0.f, 0.f, 0.f, 0.f, 0.f};

    int e = beg;
    for (; e + 2 <= end; e += 2) {
        uint2 p0 = ue[e], p1 = ue[e + 1];
        float w0 = __uint_as_float(p0.y), w1 = __uint_as_float(p1.y);
        uint4 u0 = *(const uint4*)(T + (size_t)p0.x * O + o * 8);
        uint4 u1 = *(const uint4*)(T + (size_t)p1.x * O + o * 8);
        ACC8(a, u0, w0);
        ACC8(c, u1, w1);
    }
    if (e < end) {
        uint2 p0 = ue[e];
        float w0 = __uint_as_float(p0.y);
        uint4 u0 = *(const uint4*)(T + (size_t)p0.x * O + o * 8);
        ACC8(a, u0, w0);
    }

    float4 b0 = *(const float4*)(bias2 + o * 8);
    float4 b1 = *(const float4*)(bias2 + o * 8 + 4);
    float4 v0, v1;
    v0.x = a[0] + c[0] + b0.x; v0.y = a[1] + c[1] + b0.y;
    v0.z = a[2] + c[2] + b0.z; v0.w = a[3] + c[3] + b0.w;
    v1.x = a[4] + c[4] + b1.x; v1.y = a[5] + c[5] + b1.y;
    v1.z = a[6] + c[6] + b1.z; v1.w = a[7] + c[7] + b1.w;
    *(float4*)(out + (size_t)node * O + o * 8)     = v0;
    *(float4*)(out + (size_t)node * O + o * 8 + 4) = v1;
}

extern "C" void kernel_launch(void* const* d_in, const int* in_sizes, int n_in,
                              void* d_out, int out_size, void* d_ws, size_t ws_size,
                              hipStream_t stream) {
    const float* embed  = (const float*)d_in[0];
    const float* weight = (const float*)d_in[1];
    const float* bias1  = (const float*)d_in[2];
    const float* bias2  = (const float*)d_in[3];
    const int*   esrc   = (const int*)d_in[4];
    const int*   edst   = (const int*)d_in[5];
    float* out = (float*)d_out;

    const int N = in_sizes[0] / H;
    const int E = in_sizes[4] / RELS;
    const int RN = RELS * N;
    const int RE = RELS * E;

    char* p = (char*)d_ws;
    auto alloc = [&](size_t bytes) {
        char* q = p;
        p += (bytes + 255) & ~(size_t)255;
        return q;
    };
    int* cnt    = (int*)alloc((size_t)RN * 4);
    int* offs2  = (int*)alloc(((size_t)N + 1) * 4);
    int* cursor = (int*)alloc((size_t)RN * 4);
    int* bsum   = (int*)alloc(4096);
    uint2* ue   = (uint2*)alloc((size_t)RE * 8);
    unsigned short* eb  = (unsigned short*)alloc((size_t)N * H * 2);
    unsigned short* h1  = (unsigned short*)alloc((size_t)N * H * 2);
    unsigned short* WT  = (unsigned short*)alloc((size_t)RELS * O * H * 2);
    unsigned short* T   = (unsigned short*)alloc((size_t)RELS * N * O * 2);

    hipMemsetAsync(cnt, 0, (size_t)RN * 4, stream);

    int n4 = N * H / 4;
    int wtot = RELS * O * H;
    int b_cvt = (n4 + 255) / 256;
    int b_w   = (wtot + 255) / 256;
    int b_h   = (RE + 255) / 256;
    k_prep<<<b_cvt + b_w + b_h, 256, 0, stream>>>(embed, eb, weight, WT, edst, cnt,
                                                  n4, wtot, E, RE, N, b_cvt, b_w);

    int nb = (N + 1023) / 1024;
    k_scan1<<<nb, 256, 0, stream>>>(cnt, offs2, bsum, N, N);
    k_scan2<<<1, 512, 0, stream>>>(bsum, nb);
    k_scan3c<<<(N + 255) / 256, 256, 0, stream>>>(offs2, bsum, cnt, cursor, N, RE, N);

    k_fill<<<(RE + 255) / 256, 256, 0, stream>>>(esrc, edst, cnt, cursor, ue, E, RE, N);

    k_pull1<<<(N + 15) / 16, 256, 0, stream>>>(eb, offs2, ue, bias1, h1, N);

    k_gemm<<<(N + 127) / 128, 256, 0, stream>>>(h1, WT, T, N);

    k_pull2<<<(N + 31) / 32, 256, 0, stream>>>(T, offs2, ue, bias2, out, N);
}